// Round 7
// baseline (334.280 us; speedup 1.0000x reference)
//
#include <hip/hip_runtime.h>
#include <hip/hip_bf16.h>

// Pipeline (no global atomics — rounds 3/4 showed global atomics write through
// to HBM per-op on MI355X). Round-5 lesson: build kernels need >=256 blocks.
// Round-7: NRANGE=8/NCHUNK=32 halves redundant edge re-reads; 1-dispatch scan;
// 2-edges-per-wave gather; float4-LDS dual GEMM.

#define NCHUNK 32   // edge chunks
#define NRANGE 8    // node ranges (range = 6250 for N=50000)
#define HIST_MAX 6272

// ---------- partial histograms: a=0 deg over row, a=1 indeg over col ----------
__global__ __launch_bounds__(1024) void k_hist(const int* __restrict__ ei,
                                               int* __restrict__ partial,
                                               int N, int E, int range) {
  __shared__ int hist[HIST_MAX];
  int c = blockIdx.x % NCHUNK;
  int r = (blockIdx.x / NCHUNK) % NRANGE;
  int a = blockIdx.x / (NCHUNK * NRANGE);
  const int* ids = ei + (size_t)a * E;
  int lo = r * range;
  int hi = min(N, lo + range);
  int len = hi - lo;
  for (int i = threadIdx.x; i < len; i += 1024) hist[i] = 0;
  __syncthreads();
  int e0 = (int)((long long)E * c / NCHUNK);
  int e1 = (int)((long long)E * (c + 1) / NCHUNK);
  for (int e = e0 + threadIdx.x; e < e1; e += 1024) {
    int id = ids[e];
    if (id >= lo && id < hi) atomicAdd(&hist[id - lo], 1);  // LDS atomic
  }
  __syncthreads();
  int* dst = partial + ((size_t)a * NCHUNK + c) * N + lo;
  for (int i = threadIdx.x; i < len; i += 1024) dst[i] = hist[i];
}

// ---------- reduce partials -> dinv, indeg ----------
__global__ __launch_bounds__(256) void k_reduce_dinv(const int* __restrict__ partial,
                                                     float* __restrict__ dinv,
                                                     int* __restrict__ indeg, int N) {
  int n = blockIdx.x * 256 + threadIdx.x;
  if (n >= N) return;
  int deg = 0, ind = 0;
#pragma unroll
  for (int c = 0; c < NCHUNK; ++c) {
    deg += partial[(size_t)c * N + n];
    ind += partial[((size_t)NCHUNK + c) * N + n];
  }
  dinv[n] = (deg > 0) ? (1.0f / sqrtf((float)deg)) : 0.0f;
  indeg[n] = ind;
}

// ---------- single-dispatch exclusive scan: ptr = exscan(indeg) ----------
// One 1024-thread block; each thread owns ceil(N/1024) contiguous nodes.
__global__ __launch_bounds__(1024) void k_scan(const int* __restrict__ indeg,
                                               int* __restrict__ ptr, int N) {
  __shared__ int s[1024];
  const int tid = threadIdx.x;
  const int npt = (N + 1023) >> 10;
  int lo = tid * npt;
  int hi = min(N, lo + npt);
  int sum = 0;
  for (int i = lo; i < hi; ++i) sum += indeg[i];
  s[tid] = sum;
  __syncthreads();
  for (int off = 1; off < 1024; off <<= 1) {
    int v = (tid >= off) ? s[tid - off] : 0;
    __syncthreads();
    s[tid] += v;
    __syncthreads();
  }
  int run = s[tid] - sum;  // exclusive prefix
  for (int i = lo; i < hi; ++i) {
    ptr[i] = run;
    run += indeg[i];
  }
}

// ---------- per-chunk placement bases ----------
__global__ __launch_bounds__(256) void k_base(const int* __restrict__ partial,
                                              const int* __restrict__ ptr,
                                              int* __restrict__ base, int N) {
  int n = blockIdx.x * 256 + threadIdx.x;
  if (n >= N) return;
  int run = ptr[n];
#pragma unroll
  for (int c = 0; c < NCHUNK; ++c) {
    base[(size_t)c * N + n] = run;
    run += partial[((size_t)NCHUNK + c) * N + n];
  }
}

// ---------- counting-sort binning (LDS atomics; base slice preloaded) ----------
__global__ __launch_bounds__(1024) void k_bin2(const int* __restrict__ ei,
                                               const int* __restrict__ base,
                                               int* __restrict__ csr_row,
                                               int N, int E, int range) {
  __shared__ int cnt[HIST_MAX];
  __shared__ int base_s[HIST_MAX];
  int c = blockIdx.x % NCHUNK;
  int r = blockIdx.x / NCHUNK;
  const int* row = ei;
  const int* col = ei + E;
  int lo = r * range;
  int hi = min(N, lo + range);
  int len = hi - lo;
  const int* bsrc = base + (size_t)c * N + lo;
  for (int i = threadIdx.x; i < len; i += 1024) {
    cnt[i] = 0;
    base_s[i] = bsrc[i];
  }
  __syncthreads();
  int e0 = (int)((long long)E * c / NCHUNK);
  int e1 = (int)((long long)E * (c + 1) / NCHUNK);
  for (int e = e0 + threadIdx.x; e < e1; e += 1024) {
    int cl = col[e];
    int rw = row[e];
    if (cl >= lo && cl < hi) {
      int off = atomicAdd(&cnt[cl - lo], 1);   // LDS atomic
      csr_row[base_s[cl - lo] + off] = rw;     // plain store (L2-absorbed)
    }
  }
}

// ---------- dual GEMM: t = h@Wn (bf16 out), agg = h@Wi + bias ----------
// h and agg may ALIAS (in-place layer 2): block owns rows [64b,64b+64),
// stages each 32-row group into LDS before overwriting it; groups disjoint.
// LDS reads: h as float4 broadcast (stride-68 rows), W as stride-1 b32.
template <bool RELU>
__global__ __launch_bounds__(256) void k_dual_gemm(
    const float* h,
    const float* __restrict__ Wn,
    const float* __restrict__ Wi,
    const float* __restrict__ bias,
    __hip_bfloat16* __restrict__ t, float* agg, int N) {
  __shared__ float Wn_s[64 * 64];
  __shared__ float Wi_s[64 * 64];
  __shared__ float b_s[64];
  __shared__ float h_s[32 * 68];   // 32 rows, stride 68 (pad kills store conflicts)

  const int tid = threadIdx.x;
  {
    const float4* Wn4 = (const float4*)Wn;
    const float4* Wi4 = (const float4*)Wi;
    for (int i = tid; i < 1024; i += 256) {
      ((float4*)Wn_s)[i] = Wn4[i];
      ((float4*)Wi_s)[i] = Wi4[i];
    }
  }
  if (tid < 64) b_s[tid] = bias[tid];

  const int j = tid & 63;      // output column
  const int rg = tid >> 6;     // row group 0..3 -> rows rg*8..rg*8+7
  const int r0 = blockIdx.x * 64;

  for (int g = 0; g < 2; ++g) {
    __syncthreads();  // protect h_s from prior readers; fences W staging (g=0)
    for (int v = tid; v < 512; v += 256) {
      int rr = v >> 4;
      int c4 = v & 15;
      int rload = r0 + g * 32 + rr;
      float4 val = make_float4(0.f, 0.f, 0.f, 0.f);
      if (rload < N) {
        val = *(const float4*)&h[(size_t)rload * 64 + c4 * 4];
        if (RELU) {
          val.x = fmaxf(val.x, 0.f); val.y = fmaxf(val.y, 0.f);
          val.z = fmaxf(val.z, 0.f); val.w = fmaxf(val.w, 0.f);
        }
      }
      *(float4*)&h_s[rr * 68 + c4 * 4] = val;
    }
    __syncthreads();

    float acc_t[8] = {0.f, 0.f, 0.f, 0.f, 0.f, 0.f, 0.f, 0.f};
    float acc_a[8] = {0.f, 0.f, 0.f, 0.f, 0.f, 0.f, 0.f, 0.f};
    for (int k4 = 0; k4 < 16; ++k4) {
      float4 hv[8];
#pragma unroll
      for (int r = 0; r < 8; ++r)
        hv[r] = *(const float4*)&h_s[(rg * 8 + r) * 68 + k4 * 4];
#pragma unroll
      for (int kk = 0; kk < 4; ++kk) {
        int k = k4 * 4 + kk;
        float wn = Wn_s[k * 64 + j];
        float wi = Wi_s[k * 64 + j];
#pragma unroll
        for (int r = 0; r < 8; ++r) {
          float hk = ((const float*)&hv[r])[kk];
          acc_t[r] = fmaf(hk, wn, acc_t[r]);
          acc_a[r] = fmaf(hk, wi, acc_a[r]);
        }
      }
    }
#pragma unroll
    for (int r = 0; r < 8; ++r) {
      int rr = r0 + g * 32 + rg * 8 + r;
      if (rr < N) {
        t[(size_t)rr * 64 + j] = __float2bfloat16(acc_t[r]);
        agg[(size_t)rr * 64 + j] = acc_a[r] + b_s[j];
      }
    }
  }
}

// ---------- CSR gather: agg[n] += sum_e t[row_e] * dinv[row_e]*dinv[n] ----------
// One wave per node; half-wave per edge (2 edges in flight), lane covers a
// bf16x2 feature pair. Halves combined with shfl_xor(32) at the end.
__global__ __launch_bounds__(256) void k_gather(
    const int* __restrict__ csr_row, const int* __restrict__ ptr,
    const int* __restrict__ indeg, const float* __restrict__ dinv,
    const __hip_bfloat16* __restrict__ t, float* __restrict__ agg, int N) {
  int n = blockIdx.x * 4 + (threadIdx.x >> 6);
  if (n >= N) return;
  int lane = threadIdx.x & 63;
  int half = lane >> 5;        // 0/1: which edge of the pair
  int fl = lane & 31;          // feature pair index (features 2fl, 2fl+1)
  int i0 = ptr[n];
  int end = i0 + indeg[n];
  float dn = dinv[n];

  float2 acc = make_float2(0.f, 0.f);
  if (half == 0) acc = *(const float2*)&agg[(size_t)n * 64 + 2 * fl];

  int i = i0 + half;
  for (; i + 2 < end; i += 4) {   // two edges per half per iter
    int ra = csr_row[i];
    int rb = csr_row[i + 2];
    float na = dinv[ra] * dn;
    float nb = dinv[rb] * dn;
    __hip_bfloat162 va = *(const __hip_bfloat162*)&t[(size_t)ra * 64 + 2 * fl];
    __hip_bfloat162 vb = *(const __hip_bfloat162*)&t[(size_t)rb * 64 + 2 * fl];
    acc.x = fmaf(__bfloat162float(va.x), na, acc.x);
    acc.y = fmaf(__bfloat162float(va.y), na, acc.y);
    acc.x = fmaf(__bfloat162float(vb.x), nb, acc.x);
    acc.y = fmaf(__bfloat162float(vb.y), nb, acc.y);
  }
  for (; i < end; i += 2) {
    int ra = csr_row[i];
    float na = dinv[ra] * dn;
    __hip_bfloat162 va = *(const __hip_bfloat162*)&t[(size_t)ra * 64 + 2 * fl];
    acc.x = fmaf(__bfloat162float(va.x), na, acc.x);
    acc.y = fmaf(__bfloat162float(va.y), na, acc.y);
  }
  acc.x += __shfl_xor(acc.x, 32);
  acc.y += __shfl_xor(acc.y, 32);
  if (half == 0) *(float2*)&agg[(size_t)n * 64 + 2 * fl] = acc;
}

// ---------- output GEMM: out = relu(h) @ Wo + bo ----------
__global__ __launch_bounds__(256) void k_out_gemm(
    const float* __restrict__ h,
    const float* __restrict__ Wo,   // [64,32]
    const float* __restrict__ bo,   // [32]
    float* __restrict__ out, int N) {
  __shared__ float Wo_s[64 * 32];
  __shared__ float bo_s[32];
  __shared__ float h_s[16 * 64];

  const int tid = threadIdx.x;
  for (int i = tid; i < 2048; i += 256) Wo_s[i] = Wo[i];
  if (tid < 32) bo_s[tid] = bo[tid];

  const int j = tid & 31;
  const int rsub = tid >> 5;
  const int r0 = blockIdx.x * 64;

  for (int g = 0; g < 4; ++g) {
    __syncthreads();
#pragma unroll
    for (int i = 0; i < 4; ++i) {
      int idx = tid + i * 256;
      int rr = idx >> 6;
      int cc = idx & 63;
      int rload = r0 + g * 16 + rr;
      float v = 0.0f;
      if (rload < N) v = fmaxf(h[(size_t)rload * 64 + cc], 0.0f);
      h_s[idx] = v;
    }
    __syncthreads();
#pragma unroll
    for (int rh = 0; rh < 2; ++rh) {
      int rloc = rsub + rh * 8;
      float acc = 0.0f;
#pragma unroll 8
      for (int k = 0; k < 64; ++k)
        acc = fmaf(h_s[rloc * 64 + k], Wo_s[k * 32 + j], acc);
      int r = r0 + g * 16 + rloc;
      if (r < N) out[(size_t)r * 32 + j] = acc + bo_s[j];
    }
  }
}

extern "C" void kernel_launch(void* const* d_in, const int* in_sizes, int n_in,
                              void* d_out, int out_size, void* d_ws, size_t ws_size,
                              hipStream_t stream) {
  const float* x = (const float*)d_in[0];
  const int* ei = (const int*)d_in[1];
  const float* W_in1 = (const float*)d_in[2];
  const float* W_neigh1 = (const float*)d_in[3];
  const float* bias1 = (const float*)d_in[4];
  const float* W_in2 = (const float*)d_in[5];
  const float* W_neigh2 = (const float*)d_in[6];
  const float* bias2 = (const float*)d_in[7];
  const float* W_out = (const float*)d_in[8];
  const float* b_out = (const float*)d_in[9];
  float* out = (float*)d_out;

  const int N = in_sizes[0] / 64;
  const int E = in_sizes[1] / 2;

  // workspace: dinv, indeg, ptr, csr_row, partial(2*C*N), base(C*N),
  // t(bf16), agg(fp32). ~42 MB total (ws_size ~256 MiB per round-6 profile).
  char* ws = (char*)d_ws;
  size_t off = 0;
  auto alloc = [&](size_t bytes) -> void* {
    void* p = ws + off;
    off += (bytes + 255) & ~(size_t)255;
    return p;
  };
  float* dinv = (float*)alloc((size_t)N * 4);
  int* indeg = (int*)alloc((size_t)N * 4);
  int* ptr = (int*)alloc((size_t)N * 4);
  int* csr_row = (int*)alloc((size_t)E * 4);
  int* partial = (int*)alloc((size_t)2 * NCHUNK * N * 4);
  int* base = (int*)alloc((size_t)NCHUNK * N * 4);
  __hip_bfloat16* t = (__hip_bfloat16*)alloc((size_t)N * 64 * 2);
  float* agg = (float*)alloc((size_t)N * 64 * 4);
  (void)ws_size;

  int range = (N + NRANGE - 1) / NRANGE;  // 6250 <= HIST_MAX
  int gN = (N + 255) / 256;
  int gRows = (N + 63) / 64;
  int gNode = (N + 3) / 4;

  k_hist<<<2 * NRANGE * NCHUNK, 1024, 0, stream>>>(ei, partial, N, E, range);
  k_reduce_dinv<<<gN, 256, 0, stream>>>(partial, dinv, indeg, N);
  k_scan<<<1, 1024, 0, stream>>>(indeg, ptr, N);
  k_base<<<gN, 256, 0, stream>>>(partial, ptr, base, N);
  k_bin2<<<NRANGE * NCHUNK, 1024, 0, stream>>>(ei, base, csr_row, N, E, range);

  // layer 1
  k_dual_gemm<false><<<gRows, 256, 0, stream>>>(x, W_neigh1, W_in1, bias1, t, agg, N);
  k_gather<<<gNode, 256, 0, stream>>>(csr_row, ptr, indeg, dinv, t, agg, N);

  // layer 2 (in-place on agg)
  k_dual_gemm<true><<<gRows, 256, 0, stream>>>(agg, W_neigh2, W_in2, bias2, t, agg, N);
  k_gather<<<gNode, 256, 0, stream>>>(csr_row, ptr, indeg, dinv, t, agg, N);

  // output
  k_out_gemm<<<gRows, 256, 0, stream>>>(agg, W_out, b_out, out, N);
}

// Round 8
// 272.104 us; speedup vs baseline: 1.2285x; 1.2285x over previous
//
#include <hip/hip_runtime.h>
#include <hip/hip_bf16.h>

// Pipeline (no global atomics — global atomics write through to HBM per-op on
// MI355X; rounds 3/4). Build kernels need >=256 blocks (round 5) AND the scan
// needs multi-block dispatches (round 7: single-block scan = 75 us at 0.15%
// occupancy). Scan is the round-6 3-dispatch hierarchical version.

#define NCHUNK 32   // edge chunks
#define NRANGE 8    // node ranges (range = 6250 for N=50000)
#define HIST_MAX 6272

// ---------- partial histograms: a=0 deg over row, a=1 indeg over col ----------
__global__ __launch_bounds__(1024) void k_hist(const int* __restrict__ ei,
                                               int* __restrict__ partial,
                                               int N, int E, int range) {
  __shared__ int hist[HIST_MAX];
  int c = blockIdx.x % NCHUNK;
  int r = (blockIdx.x / NCHUNK) % NRANGE;
  int a = blockIdx.x / (NCHUNK * NRANGE);
  const int* ids = ei + (size_t)a * E;
  int lo = r * range;
  int hi = min(N, lo + range);
  int len = hi - lo;
  for (int i = threadIdx.x; i < len; i += 1024) hist[i] = 0;
  __syncthreads();
  int e0 = (int)((long long)E * c / NCHUNK);
  int e1 = (int)((long long)E * (c + 1) / NCHUNK);
  for (int e = e0 + threadIdx.x; e < e1; e += 1024) {
    int id = ids[e];
    if (id >= lo && id < hi) atomicAdd(&hist[id - lo], 1);  // LDS atomic
  }
  __syncthreads();
  int* dst = partial + ((size_t)a * NCHUNK + c) * N + lo;
  for (int i = threadIdx.x; i < len; i += 1024) dst[i] = hist[i];
}

// ---------- reduce partials -> dinv, indeg ----------
__global__ __launch_bounds__(256) void k_reduce_dinv(const int* __restrict__ partial,
                                                     float* __restrict__ dinv,
                                                     int* __restrict__ indeg, int N) {
  int n = blockIdx.x * 256 + threadIdx.x;
  if (n >= N) return;
  int deg = 0, ind = 0;
#pragma unroll
  for (int c = 0; c < NCHUNK; ++c) {
    deg += partial[(size_t)c * N + n];
    ind += partial[((size_t)NCHUNK + c) * N + n];
  }
  dinv[n] = (deg > 0) ? (1.0f / sqrtf((float)deg)) : 0.0f;
  indeg[n] = ind;
}

// ---------- 3-dispatch hierarchical exclusive scan: ptr = exscan(indeg) ----------
__global__ __launch_bounds__(1024) void k_scan1(const int* __restrict__ in,
                                                int* __restrict__ out,
                                                int* __restrict__ bsum, int n) {
  __shared__ int s[1024];
  int g = blockIdx.x * 1024 + threadIdx.x;
  int v = (g < n) ? in[g] : 0;
  s[threadIdx.x] = v;
  __syncthreads();
  for (int off = 1; off < 1024; off <<= 1) {
    int tv = (threadIdx.x >= off) ? s[threadIdx.x - off] : 0;
    __syncthreads();
    s[threadIdx.x] += tv;
    __syncthreads();
  }
  if (g < n) out[g] = s[threadIdx.x] - v;  // exclusive
  if (threadIdx.x == 1023) bsum[blockIdx.x] = s[1023];
}

__global__ void k_scan2(int* __restrict__ bsum, int nb) {
  if (threadIdx.x == 0 && blockIdx.x == 0) {
    int acc = 0;
    for (int i = 0; i < nb; ++i) { int v = bsum[i]; bsum[i] = acc; acc += v; }
  }
}

__global__ __launch_bounds__(1024) void k_scan3(int* __restrict__ out,
                                                const int* __restrict__ bsum, int n) {
  int g = blockIdx.x * 1024 + threadIdx.x;
  if (g < n) out[g] += bsum[blockIdx.x];
}

// ---------- per-chunk placement bases ----------
__global__ __launch_bounds__(256) void k_base(const int* __restrict__ partial,
                                              const int* __restrict__ ptr,
                                              int* __restrict__ base, int N) {
  int n = blockIdx.x * 256 + threadIdx.x;
  if (n >= N) return;
  int run = ptr[n];
#pragma unroll
  for (int c = 0; c < NCHUNK; ++c) {
    base[(size_t)c * N + n] = run;
    run += partial[((size_t)NCHUNK + c) * N + n];
  }
}

// ---------- counting-sort binning (LDS atomics; base slice preloaded) ----------
__global__ __launch_bounds__(1024) void k_bin2(const int* __restrict__ ei,
                                               const int* __restrict__ base,
                                               int* __restrict__ csr_row,
                                               int N, int E, int range) {
  __shared__ int cnt[HIST_MAX];
  __shared__ int base_s[HIST_MAX];
  int c = blockIdx.x % NCHUNK;
  int r = blockIdx.x / NCHUNK;
  const int* row = ei;
  const int* col = ei + E;
  int lo = r * range;
  int hi = min(N, lo + range);
  int len = hi - lo;
  const int* bsrc = base + (size_t)c * N + lo;
  for (int i = threadIdx.x; i < len; i += 1024) {
    cnt[i] = 0;
    base_s[i] = bsrc[i];
  }
  __syncthreads();
  int e0 = (int)((long long)E * c / NCHUNK);
  int e1 = (int)((long long)E * (c + 1) / NCHUNK);
  for (int e = e0 + threadIdx.x; e < e1; e += 1024) {
    int cl = col[e];
    int rw = row[e];
    if (cl >= lo && cl < hi) {
      int off = atomicAdd(&cnt[cl - lo], 1);   // LDS atomic
      csr_row[base_s[cl - lo] + off] = rw;     // plain store (L2-absorbed)
    }
  }
}

// ---------- dual GEMM: t = h@Wn (bf16 out), agg = h@Wi + bias ----------
// h and agg may ALIAS (in-place layer 2): block owns rows [64b,64b+64),
// stages each 32-row group into LDS before overwriting it; groups disjoint.
template <bool RELU>
__global__ __launch_bounds__(256) void k_dual_gemm(
    const float* h,
    const float* __restrict__ Wn,
    const float* __restrict__ Wi,
    const float* __restrict__ bias,
    __hip_bfloat16* __restrict__ t, float* agg, int N) {
  __shared__ float Wn_s[64 * 64];
  __shared__ float Wi_s[64 * 64];
  __shared__ float b_s[64];
  __shared__ float h_s[32 * 68];   // 32 rows, stride 68 (pad kills store conflicts)

  const int tid = threadIdx.x;
  {
    const float4* Wn4 = (const float4*)Wn;
    const float4* Wi4 = (const float4*)Wi;
    for (int i = tid; i < 1024; i += 256) {
      ((float4*)Wn_s)[i] = Wn4[i];
      ((float4*)Wi_s)[i] = Wi4[i];
    }
  }
  if (tid < 64) b_s[tid] = bias[tid];

  const int j = tid & 63;      // output column
  const int rg = tid >> 6;     // row group 0..3 -> rows rg*8..rg*8+7
  const int r0 = blockIdx.x * 64;

  for (int g = 0; g < 2; ++g) {
    __syncthreads();  // protect h_s from prior readers; fences W staging (g=0)
    for (int v = tid; v < 512; v += 256) {
      int rr = v >> 4;
      int c4 = v & 15;
      int rload = r0 + g * 32 + rr;
      float4 val = make_float4(0.f, 0.f, 0.f, 0.f);
      if (rload < N) {
        val = *(const float4*)&h[(size_t)rload * 64 + c4 * 4];
        if (RELU) {
          val.x = fmaxf(val.x, 0.f); val.y = fmaxf(val.y, 0.f);
          val.z = fmaxf(val.z, 0.f); val.w = fmaxf(val.w, 0.f);
        }
      }
      *(float4*)&h_s[rr * 68 + c4 * 4] = val;
    }
    __syncthreads();

    float acc_t[8] = {0.f, 0.f, 0.f, 0.f, 0.f, 0.f, 0.f, 0.f};
    float acc_a[8] = {0.f, 0.f, 0.f, 0.f, 0.f, 0.f, 0.f, 0.f};
    for (int k4 = 0; k4 < 16; ++k4) {
      float4 hv[8];
#pragma unroll
      for (int r = 0; r < 8; ++r)
        hv[r] = *(const float4*)&h_s[(rg * 8 + r) * 68 + k4 * 4];
#pragma unroll
      for (int kk = 0; kk < 4; ++kk) {
        int k = k4 * 4 + kk;
        float wn = Wn_s[k * 64 + j];
        float wi = Wi_s[k * 64 + j];
#pragma unroll
        for (int r = 0; r < 8; ++r) {
          float hk = ((const float*)&hv[r])[kk];
          acc_t[r] = fmaf(hk, wn, acc_t[r]);
          acc_a[r] = fmaf(hk, wi, acc_a[r]);
        }
      }
    }
#pragma unroll
    for (int r = 0; r < 8; ++r) {
      int rr = r0 + g * 32 + rg * 8 + r;
      if (rr < N) {
        t[(size_t)rr * 64 + j] = __float2bfloat16(acc_t[r]);
        agg[(size_t)rr * 64 + j] = acc_a[r] + b_s[j];
      }
    }
  }
}

// ---------- CSR gather: agg[n] += sum_e t[row_e] * dinv[row_e]*dinv[n] ----------
// One wave per node; half-wave per edge (2 edges in flight), lane covers a
// bf16x2 feature pair. Halves combined with shfl_xor(32) at the end.
__global__ __launch_bounds__(256) void k_gather(
    const int* __restrict__ csr_row, const int* __restrict__ ptr,
    const int* __restrict__ indeg, const float* __restrict__ dinv,
    const __hip_bfloat16* __restrict__ t, float* __restrict__ agg, int N) {
  int n = blockIdx.x * 4 + (threadIdx.x >> 6);
  if (n >= N) return;
  int lane = threadIdx.x & 63;
  int half = lane >> 5;        // 0/1: which edge of the pair
  int fl = lane & 31;          // feature pair index (features 2fl, 2fl+1)
  int i0 = ptr[n];
  int end = i0 + indeg[n];
  float dn = dinv[n];

  float2 acc = make_float2(0.f, 0.f);
  if (half == 0) acc = *(const float2*)&agg[(size_t)n * 64 + 2 * fl];

  int i = i0 + half;
  for (; i + 2 < end; i += 4) {   // two edges per half per iter
    int ra = csr_row[i];
    int rb = csr_row[i + 2];
    float na = dinv[ra] * dn;
    float nb = dinv[rb] * dn;
    __hip_bfloat162 va = *(const __hip_bfloat162*)&t[(size_t)ra * 64 + 2 * fl];
    __hip_bfloat162 vb = *(const __hip_bfloat162*)&t[(size_t)rb * 64 + 2 * fl];
    acc.x = fmaf(__bfloat162float(va.x), na, acc.x);
    acc.y = fmaf(__bfloat162float(va.y), na, acc.y);
    acc.x = fmaf(__bfloat162float(vb.x), nb, acc.x);
    acc.y = fmaf(__bfloat162float(vb.y), nb, acc.y);
  }
  for (; i < end; i += 2) {
    int ra = csr_row[i];
    float na = dinv[ra] * dn;
    __hip_bfloat162 va = *(const __hip_bfloat162*)&t[(size_t)ra * 64 + 2 * fl];
    acc.x = fmaf(__bfloat162float(va.x), na, acc.x);
    acc.y = fmaf(__bfloat162float(va.y), na, acc.y);
  }
  acc.x += __shfl_xor(acc.x, 32);
  acc.y += __shfl_xor(acc.y, 32);
  if (half == 0) *(float2*)&agg[(size_t)n * 64 + 2 * fl] = acc;
}

// ---------- output GEMM: out = relu(h) @ Wo + bo ----------
__global__ __launch_bounds__(256) void k_out_gemm(
    const float* __restrict__ h,
    const float* __restrict__ Wo,   // [64,32]
    const float* __restrict__ bo,   // [32]
    float* __restrict__ out, int N) {
  __shared__ float Wo_s[64 * 32];
  __shared__ float bo_s[32];
  __shared__ float h_s[16 * 64];

  const int tid = threadIdx.x;
  for (int i = tid; i < 2048; i += 256) Wo_s[i] = Wo[i];
  if (tid < 32) bo_s[tid] = bo[tid];

  const int j = tid & 31;
  const int rsub = tid >> 5;
  const int r0 = blockIdx.x * 64;

  for (int g = 0; g < 4; ++g) {
    __syncthreads();
#pragma unroll
    for (int i = 0; i < 4; ++i) {
      int idx = tid + i * 256;
      int rr = idx >> 6;
      int cc = idx & 63;
      int rload = r0 + g * 16 + rr;
      float v = 0.0f;
      if (rload < N) v = fmaxf(h[(size_t)rload * 64 + cc], 0.0f);
      h_s[idx] = v;
    }
    __syncthreads();
#pragma unroll
    for (int rh = 0; rh < 2; ++rh) {
      int rloc = rsub + rh * 8;
      float acc = 0.0f;
#pragma unroll 8
      for (int k = 0; k < 64; ++k)
        acc = fmaf(h_s[rloc * 64 + k], Wo_s[k * 32 + j], acc);
      int r = r0 + g * 16 + rloc;
      if (r < N) out[(size_t)r * 32 + j] = acc + bo_s[j];
    }
  }
}

extern "C" void kernel_launch(void* const* d_in, const int* in_sizes, int n_in,
                              void* d_out, int out_size, void* d_ws, size_t ws_size,
                              hipStream_t stream) {
  const float* x = (const float*)d_in[0];
  const int* ei = (const int*)d_in[1];
  const float* W_in1 = (const float*)d_in[2];
  const float* W_neigh1 = (const float*)d_in[3];
  const float* bias1 = (const float*)d_in[4];
  const float* W_in2 = (const float*)d_in[5];
  const float* W_neigh2 = (const float*)d_in[6];
  const float* bias2 = (const float*)d_in[7];
  const float* W_out = (const float*)d_in[8];
  const float* b_out = (const float*)d_in[9];
  float* out = (float*)d_out;

  const int N = in_sizes[0] / 64;
  const int E = in_sizes[1] / 2;

  // workspace: dinv, indeg, ptr, bsum, csr_row, partial(2*C*N), base(C*N),
  // t(bf16), agg(fp32). ~42 MB total (ws_size ~256 MiB per round-6 profile).
  char* ws = (char*)d_ws;
  size_t off = 0;
  auto alloc = [&](size_t bytes) -> void* {
    void* p = ws + off;
    off += (bytes + 255) & ~(size_t)255;
    return p;
  };
  float* dinv = (float*)alloc((size_t)N * 4);
  int* indeg = (int*)alloc((size_t)N * 4);
  int* ptr = (int*)alloc((size_t)N * 4);
  int* bsum = (int*)alloc(256);
  int* csr_row = (int*)alloc((size_t)E * 4);
  int* partial = (int*)alloc((size_t)2 * NCHUNK * N * 4);
  int* base = (int*)alloc((size_t)NCHUNK * N * 4);
  __hip_bfloat16* t = (__hip_bfloat16*)alloc((size_t)N * 64 * 2);
  float* agg = (float*)alloc((size_t)N * 64 * 4);
  (void)ws_size;

  int range = (N + NRANGE - 1) / NRANGE;  // 6250 <= HIST_MAX
  int gN = (N + 255) / 256;
  int gRows = (N + 63) / 64;
  int gNode = (N + 3) / 4;
  int nb = (N + 1023) / 1024;

  k_hist<<<2 * NRANGE * NCHUNK, 1024, 0, stream>>>(ei, partial, N, E, range);
  k_reduce_dinv<<<gN, 256, 0, stream>>>(partial, dinv, indeg, N);
  k_scan1<<<nb, 1024, 0, stream>>>(indeg, ptr, bsum, N);
  k_scan2<<<1, 64, 0, stream>>>(bsum, nb);
  k_scan3<<<nb, 1024, 0, stream>>>(ptr, bsum, N);
  k_base<<<gN, 256, 0, stream>>>(partial, ptr, base, N);
  k_bin2<<<NRANGE * NCHUNK, 1024, 0, stream>>>(ei, base, csr_row, N, E, range);

  // layer 1
  k_dual_gemm<false><<<gRows, 256, 0, stream>>>(x, W_neigh1, W_in1, bias1, t, agg, N);
  k_gather<<<gNode, 256, 0, stream>>>(csr_row, ptr, indeg, dinv, t, agg, N);

  // layer 2 (in-place on agg)
  k_dual_gemm<true><<<gRows, 256, 0, stream>>>(agg, W_neigh2, W_in2, bias2, t, agg, N);
  k_gather<<<gNode, 256, 0, stream>>>(csr_row, ptr, indeg, dinv, t, agg, N);

  // output
  k_out_gemm<<<gRows, 256, 0, stream>>>(agg, W_out, b_out, out, N);
}

// Round 9
// 251.232 us; speedup vs baseline: 1.3306x; 1.0831x over previous
//
#include <hip/hip_runtime.h>
#include <hip/hip_bf16.h>

// Pipeline (no global atomics — they write through to HBM per-op on MI355X;
// rounds 3/4). Build kernels need >=256 blocks and multi-block scans
// (rounds 5/7). Round 9: quarter-wave gather (8 edges in flight), fused
// dinv+scan1 and scan3+base (13 -> 10 dispatches).

#define NCHUNK 32   // edge chunks
#define NRANGE 8    // node ranges (range = 6250 for N=50000)
#define HIST_MAX 6272

// ---------- partial histograms: a=0 deg over row, a=1 indeg over col ----------
__global__ __launch_bounds__(1024) void k_hist(const int* __restrict__ ei,
                                               int* __restrict__ partial,
                                               int N, int E, int range) {
  __shared__ int hist[HIST_MAX];
  int c = blockIdx.x % NCHUNK;
  int r = (blockIdx.x / NCHUNK) % NRANGE;
  int a = blockIdx.x / (NCHUNK * NRANGE);
  const int* ids = ei + (size_t)a * E;
  int lo = r * range;
  int hi = min(N, lo + range);
  int len = hi - lo;
  for (int i = threadIdx.x; i < len; i += 1024) hist[i] = 0;
  __syncthreads();
  int e0 = (int)((long long)E * c / NCHUNK);
  int e1 = (int)((long long)E * (c + 1) / NCHUNK);
  for (int e = e0 + threadIdx.x; e < e1; e += 1024) {
    int id = ids[e];
    if (id >= lo && id < hi) atomicAdd(&hist[id - lo], 1);  // LDS atomic
  }
  __syncthreads();
  int* dst = partial + ((size_t)a * NCHUNK + c) * N + lo;
  for (int i = threadIdx.x; i < len; i += 1024) dst[i] = hist[i];
}

// ---------- fused: reduce partials -> dinv/indeg, then in-block exscan ----------
// grid = ceil(N/1024) x 1024. Writes dinv, indeg, block-local exclusive scan
// into ptr, per-block totals into bsum.
__global__ __launch_bounds__(1024) void k_dinv_scan(const int* __restrict__ partial,
                                                    float* __restrict__ dinv,
                                                    int* __restrict__ indeg,
                                                    int* __restrict__ ptr,
                                                    int* __restrict__ bsum, int N) {
  __shared__ int s[1024];
  int g = blockIdx.x * 1024 + threadIdx.x;
  int deg = 0, ind = 0;
  if (g < N) {
#pragma unroll
    for (int c = 0; c < NCHUNK; ++c) {
      deg += partial[(size_t)c * N + g];
      ind += partial[((size_t)NCHUNK + c) * N + g];
    }
    dinv[g] = (deg > 0) ? (1.0f / sqrtf((float)deg)) : 0.0f;
    indeg[g] = ind;
  }
  s[threadIdx.x] = ind;
  __syncthreads();
  for (int off = 1; off < 1024; off <<= 1) {
    int tv = (threadIdx.x >= off) ? s[threadIdx.x - off] : 0;
    __syncthreads();
    s[threadIdx.x] += tv;
    __syncthreads();
  }
  if (g < N) ptr[g] = s[threadIdx.x] - ind;  // exclusive within block
  if (threadIdx.x == 1023) bsum[blockIdx.x] = s[1023];
}

__global__ void k_scan2(int* __restrict__ bsum, int nb) {
  if (threadIdx.x == 0 && blockIdx.x == 0) {
    int acc = 0;
    for (int i = 0; i < nb; ++i) { int v = bsum[i]; bsum[i] = acc; acc += v; }
  }
}

// ---------- fused: add block offset to ptr + emit per-chunk placement bases ----------
__global__ __launch_bounds__(256) void k_base(const int* __restrict__ partial,
                                              const int* __restrict__ bsum,
                                              int* __restrict__ ptr,
                                              int* __restrict__ base, int N) {
  int n = blockIdx.x * 256 + threadIdx.x;
  if (n >= N) return;
  int run = ptr[n] + bsum[n >> 10];
  ptr[n] = run;                      // final global exclusive scan
#pragma unroll
  for (int c = 0; c < NCHUNK; ++c) {
    base[(size_t)c * N + n] = run;
    run += partial[((size_t)NCHUNK + c) * N + n];
  }
}

// ---------- counting-sort binning (LDS atomics; base slice preloaded) ----------
__global__ __launch_bounds__(1024) void k_bin2(const int* __restrict__ ei,
                                               const int* __restrict__ base,
                                               int* __restrict__ csr_row,
                                               int N, int E, int range) {
  __shared__ int cnt[HIST_MAX];
  __shared__ int base_s[HIST_MAX];
  int c = blockIdx.x % NCHUNK;
  int r = blockIdx.x / NCHUNK;
  const int* row = ei;
  const int* col = ei + E;
  int lo = r * range;
  int hi = min(N, lo + range);
  int len = hi - lo;
  const int* bsrc = base + (size_t)c * N + lo;
  for (int i = threadIdx.x; i < len; i += 1024) {
    cnt[i] = 0;
    base_s[i] = bsrc[i];
  }
  __syncthreads();
  int e0 = (int)((long long)E * c / NCHUNK);
  int e1 = (int)((long long)E * (c + 1) / NCHUNK);
  for (int e = e0 + threadIdx.x; e < e1; e += 1024) {
    int cl = col[e];
    int rw = row[e];
    if (cl >= lo && cl < hi) {
      int off = atomicAdd(&cnt[cl - lo], 1);   // LDS atomic
      csr_row[base_s[cl - lo] + off] = rw;     // plain store (L2-absorbed)
    }
  }
}

// ---------- dual GEMM: t = h@Wn (bf16 out), agg = h@Wi + bias ----------
// h and agg may ALIAS (in-place layer 2): block owns rows [64b,64b+64),
// stages each 32-row group into LDS before overwriting it; groups disjoint.
template <bool RELU>
__global__ __launch_bounds__(256) void k_dual_gemm(
    const float* h,
    const float* __restrict__ Wn,
    const float* __restrict__ Wi,
    const float* __restrict__ bias,
    __hip_bfloat16* __restrict__ t, float* agg, int N) {
  __shared__ float Wn_s[64 * 64];
  __shared__ float Wi_s[64 * 64];
  __shared__ float b_s[64];
  __shared__ float h_s[32 * 68];   // 32 rows, stride 68 (pad kills store conflicts)

  const int tid = threadIdx.x;
  {
    const float4* Wn4 = (const float4*)Wn;
    const float4* Wi4 = (const float4*)Wi;
    for (int i = tid; i < 1024; i += 256) {
      ((float4*)Wn_s)[i] = Wn4[i];
      ((float4*)Wi_s)[i] = Wi4[i];
    }
  }
  if (tid < 64) b_s[tid] = bias[tid];

  const int j = tid & 63;      // output column
  const int rg = tid >> 6;     // row group 0..3 -> rows rg*8..rg*8+7
  const int r0 = blockIdx.x * 64;

  for (int g = 0; g < 2; ++g) {
    __syncthreads();  // protect h_s from prior readers; fences W staging (g=0)
    for (int v = tid; v < 512; v += 256) {
      int rr = v >> 4;
      int c4 = v & 15;
      int rload = r0 + g * 32 + rr;
      float4 val = make_float4(0.f, 0.f, 0.f, 0.f);
      if (rload < N) {
        val = *(const float4*)&h[(size_t)rload * 64 + c4 * 4];
        if (RELU) {
          val.x = fmaxf(val.x, 0.f); val.y = fmaxf(val.y, 0.f);
          val.z = fmaxf(val.z, 0.f); val.w = fmaxf(val.w, 0.f);
        }
      }
      *(float4*)&h_s[rr * 68 + c4 * 4] = val;
    }
    __syncthreads();

    float acc_t[8] = {0.f, 0.f, 0.f, 0.f, 0.f, 0.f, 0.f, 0.f};
    float acc_a[8] = {0.f, 0.f, 0.f, 0.f, 0.f, 0.f, 0.f, 0.f};
    for (int k4 = 0; k4 < 16; ++k4) {
      float4 hv[8];
#pragma unroll
      for (int r = 0; r < 8; ++r)
        hv[r] = *(const float4*)&h_s[(rg * 8 + r) * 68 + k4 * 4];
#pragma unroll
      for (int kk = 0; kk < 4; ++kk) {
        int k = k4 * 4 + kk;
        float wn = Wn_s[k * 64 + j];
        float wi = Wi_s[k * 64 + j];
#pragma unroll
        for (int r = 0; r < 8; ++r) {
          float hk = ((const float*)&hv[r])[kk];
          acc_t[r] = fmaf(hk, wn, acc_t[r]);
          acc_a[r] = fmaf(hk, wi, acc_a[r]);
        }
      }
    }
#pragma unroll
    for (int r = 0; r < 8; ++r) {
      int rr = r0 + g * 32 + rg * 8 + r;
      if (rr < N) {
        t[(size_t)rr * 64 + j] = __float2bfloat16(acc_t[r]);
        agg[(size_t)rr * 64 + j] = acc_a[r] + b_s[j];
      }
    }
  }
}

// ---------- CSR gather: agg[n] += sum_e t[row_e] * dinv[row_e]*dinv[n] ----------
// One wave per node; QUARTER-wave per edge (16 lanes x bf16x4 = full 128B row),
// unrolled 2 -> 8 edges in flight. Reduce across quarters with shfl_xor 16,32.
__global__ __launch_bounds__(256) void k_gather(
    const int* __restrict__ csr_row, const int* __restrict__ ptr,
    const int* __restrict__ indeg, const float* __restrict__ dinv,
    const __hip_bfloat16* __restrict__ t, float* __restrict__ agg, int N) {
  int n = blockIdx.x * 4 + (threadIdx.x >> 6);
  if (n >= N) return;
  int lane = threadIdx.x & 63;
  int q = lane >> 4;          // quarter 0..3: which edge of the 4-group
  int fl = lane & 15;         // feature quad index (features 4fl..4fl+3)
  int i0 = ptr[n];
  int end = i0 + indeg[n];
  float dn = dinv[n];

  float4 acc = make_float4(0.f, 0.f, 0.f, 0.f);
  if (q == 0) acc = *(const float4*)&agg[(size_t)n * 64 + 4 * fl];

  int i = i0 + q;
  for (; i + 4 < end; i += 8) {   // edges i and i+4 per quarter
    int ra = csr_row[i];
    int rb = csr_row[i + 4];
    float na = dinv[ra] * dn;
    float nb = dinv[rb] * dn;
    ushort4 ua = *(const ushort4*)&t[(size_t)ra * 64 + 4 * fl];
    ushort4 ub = *(const ushort4*)&t[(size_t)rb * 64 + 4 * fl];
    float4 va, vb;
    ((unsigned*)&va)[0] = (unsigned)ua.x << 16; ((unsigned*)&va)[1] = (unsigned)ua.y << 16;
    ((unsigned*)&va)[2] = (unsigned)ua.z << 16; ((unsigned*)&va)[3] = (unsigned)ua.w << 16;
    ((unsigned*)&vb)[0] = (unsigned)ub.x << 16; ((unsigned*)&vb)[1] = (unsigned)ub.y << 16;
    ((unsigned*)&vb)[2] = (unsigned)ub.z << 16; ((unsigned*)&vb)[3] = (unsigned)ub.w << 16;
    acc.x = fmaf(va.x, na, acc.x); acc.y = fmaf(va.y, na, acc.y);
    acc.z = fmaf(va.z, na, acc.z); acc.w = fmaf(va.w, na, acc.w);
    acc.x = fmaf(vb.x, nb, acc.x); acc.y = fmaf(vb.y, nb, acc.y);
    acc.z = fmaf(vb.z, nb, acc.z); acc.w = fmaf(vb.w, nb, acc.w);
  }
  for (; i < end; i += 4) {
    int ra = csr_row[i];
    float na = dinv[ra] * dn;
    ushort4 ua = *(const ushort4*)&t[(size_t)ra * 64 + 4 * fl];
    float4 va;
    ((unsigned*)&va)[0] = (unsigned)ua.x << 16; ((unsigned*)&va)[1] = (unsigned)ua.y << 16;
    ((unsigned*)&va)[2] = (unsigned)ua.z << 16; ((unsigned*)&va)[3] = (unsigned)ua.w << 16;
    acc.x = fmaf(va.x, na, acc.x); acc.y = fmaf(va.y, na, acc.y);
    acc.z = fmaf(va.z, na, acc.z); acc.w = fmaf(va.w, na, acc.w);
  }
  // combine quarters (and the q==0 agg init rides along)
  acc.x += __shfl_xor(acc.x, 16); acc.y += __shfl_xor(acc.y, 16);
  acc.z += __shfl_xor(acc.z, 16); acc.w += __shfl_xor(acc.w, 16);
  acc.x += __shfl_xor(acc.x, 32); acc.y += __shfl_xor(acc.y, 32);
  acc.z += __shfl_xor(acc.z, 32); acc.w += __shfl_xor(acc.w, 32);
  if (q == 0) *(float4*)&agg[(size_t)n * 64 + 4 * fl] = acc;
}

// ---------- output GEMM: out = relu(h) @ Wo + bo ----------
__global__ __launch_bounds__(256) void k_out_gemm(
    const float* __restrict__ h,
    const float* __restrict__ Wo,   // [64,32]
    const float* __restrict__ bo,   // [32]
    float* __restrict__ out, int N) {
  __shared__ float Wo_s[64 * 32];
  __shared__ float bo_s[32];
  __shared__ float h_s[16 * 64];

  const int tid = threadIdx.x;
  for (int i = tid; i < 2048; i += 256) Wo_s[i] = Wo[i];
  if (tid < 32) bo_s[tid] = bo[tid];

  const int j = tid & 31;
  const int rsub = tid >> 5;
  const int r0 = blockIdx.x * 64;

  for (int g = 0; g < 4; ++g) {
    __syncthreads();
#pragma unroll
    for (int i = 0; i < 4; ++i) {
      int idx = tid + i * 256;
      int rr = idx >> 6;
      int cc = idx & 63;
      int rload = r0 + g * 16 + rr;
      float v = 0.0f;
      if (rload < N) v = fmaxf(h[(size_t)rload * 64 + cc], 0.0f);
      h_s[idx] = v;
    }
    __syncthreads();
#pragma unroll
    for (int rh = 0; rh < 2; ++rh) {
      int rloc = rsub + rh * 8;
      float acc = 0.0f;
#pragma unroll 8
      for (int k = 0; k < 64; ++k)
        acc = fmaf(h_s[rloc * 64 + k], Wo_s[k * 32 + j], acc);
      int r = r0 + g * 16 + rloc;
      if (r < N) out[(size_t)r * 32 + j] = acc + bo_s[j];
    }
  }
}

extern "C" void kernel_launch(void* const* d_in, const int* in_sizes, int n_in,
                              void* d_out, int out_size, void* d_ws, size_t ws_size,
                              hipStream_t stream) {
  const float* x = (const float*)d_in[0];
  const int* ei = (const int*)d_in[1];
  const float* W_in1 = (const float*)d_in[2];
  const float* W_neigh1 = (const float*)d_in[3];
  const float* bias1 = (const float*)d_in[4];
  const float* W_in2 = (const float*)d_in[5];
  const float* W_neigh2 = (const float*)d_in[6];
  const float* bias2 = (const float*)d_in[7];
  const float* W_out = (const float*)d_in[8];
  const float* b_out = (const float*)d_in[9];
  float* out = (float*)d_out;

  const int N = in_sizes[0] / 64;
  const int E = in_sizes[1] / 2;

  // workspace: dinv, indeg, ptr, bsum, csr_row, partial(2*C*N), base(C*N),
  // t(bf16), agg(fp32). ~42 MB (ws ~256 MiB per round-6 profile).
  char* ws = (char*)d_ws;
  size_t off = 0;
  auto alloc = [&](size_t bytes) -> void* {
    void* p = ws + off;
    off += (bytes + 255) & ~(size_t)255;
    return p;
  };
  float* dinv = (float*)alloc((size_t)N * 4);
  int* indeg = (int*)alloc((size_t)N * 4);
  int* ptr = (int*)alloc((size_t)N * 4);
  int* bsum = (int*)alloc(256);
  int* csr_row = (int*)alloc((size_t)E * 4);
  int* partial = (int*)alloc((size_t)2 * NCHUNK * N * 4);
  int* base = (int*)alloc((size_t)NCHUNK * N * 4);
  __hip_bfloat16* t = (__hip_bfloat16*)alloc((size_t)N * 64 * 2);
  float* agg = (float*)alloc((size_t)N * 64 * 4);
  (void)ws_size;

  int range = (N + NRANGE - 1) / NRANGE;  // 6250 <= HIST_MAX
  int gN = (N + 255) / 256;
  int gRows = (N + 63) / 64;
  int gNode = (N + 3) / 4;
  int nb = (N + 1023) / 1024;

  k_hist<<<2 * NRANGE * NCHUNK, 1024, 0, stream>>>(ei, partial, N, E, range);
  k_dinv_scan<<<nb, 1024, 0, stream>>>(partial, dinv, indeg, ptr, bsum, N);
  k_scan2<<<1, 64, 0, stream>>>(bsum, nb);
  k_base<<<gN, 256, 0, stream>>>(partial, bsum, ptr, base, N);
  k_bin2<<<NRANGE * NCHUNK, 1024, 0, stream>>>(ei, base, csr_row, N, E, range);

  // layer 1
  k_dual_gemm<false><<<gRows, 256, 0, stream>>>(x, W_neigh1, W_in1, bias1, t, agg, N);
  k_gather<<<gNode, 256, 0, stream>>>(csr_row, ptr, indeg, dinv, t, agg, N);

  // layer 2 (in-place on agg)
  k_dual_gemm<true><<<gRows, 256, 0, stream>>>(agg, W_neigh2, W_in2, bias2, t, agg, N);
  k_gather<<<gNode, 256, 0, stream>>>(csr_row, ptr, indeg, dinv, t, agg, N);

  // output
  k_out_gemm<<<gRows, 256, 0, stream>>>(agg, W_out, b_out, out, N);
}

// Round 10
// 236.536 us; speedup vs baseline: 1.4132x; 1.0621x over previous
//
#include <hip/hip_runtime.h>
#include <hip/hip_bf16.h>

// Pipeline (no global atomics — they write through to HBM per-op on MI355X;
// rounds 3/4). Build kernels need >=256 blocks and multi-block scans
// (rounds 5/7). Round 10: hist NRANGE 4 (50KB LDS, halves edge re-reads);
// scan2 folded into k_base; gather2+out_gemm fused (8 dispatches total).

#define NCHUNK 32     // edge chunks
#define NRANGE_H 4    // hist node ranges (range = 12500)
#define HIST_H 12544
#define NRANGE_B 8    // bin2 node ranges (range = 6250; needs 2 LDS arrays)
#define HIST_B 6272

// ---------- partial histograms: a=0 deg over row, a=1 indeg over col ----------
__global__ __launch_bounds__(1024) void k_hist(const int* __restrict__ ei,
                                               int* __restrict__ partial,
                                               int N, int E, int range) {
  __shared__ int hist[HIST_H];
  int c = blockIdx.x % NCHUNK;
  int r = (blockIdx.x / NCHUNK) % NRANGE_H;
  int a = blockIdx.x / (NCHUNK * NRANGE_H);
  const int* ids = ei + (size_t)a * E;
  int lo = r * range;
  int hi = min(N, lo + range);
  int len = hi - lo;
  for (int i = threadIdx.x; i < len; i += 1024) hist[i] = 0;
  __syncthreads();
  int e0 = (int)((long long)E * c / NCHUNK);
  int e1 = (int)((long long)E * (c + 1) / NCHUNK);
  for (int e = e0 + threadIdx.x; e < e1; e += 1024) {
    int id = ids[e];
    if (id >= lo && id < hi) atomicAdd(&hist[id - lo], 1);  // LDS atomic
  }
  __syncthreads();
  int* dst = partial + ((size_t)a * NCHUNK + c) * N + lo;
  for (int i = threadIdx.x; i < len; i += 1024) dst[i] = hist[i];
}

// ---------- fused: reduce partials -> dinv/indeg, then in-block exscan ----------
__global__ __launch_bounds__(1024) void k_dinv_scan(const int* __restrict__ partial,
                                                    float* __restrict__ dinv,
                                                    int* __restrict__ indeg,
                                                    int* __restrict__ ptr,
                                                    int* __restrict__ bsum, int N) {
  __shared__ int s[1024];
  int g = blockIdx.x * 1024 + threadIdx.x;
  int deg = 0, ind = 0;
  if (g < N) {
#pragma unroll
    for (int c = 0; c < NCHUNK; ++c) {
      deg += partial[(size_t)c * N + g];
      ind += partial[((size_t)NCHUNK + c) * N + g];
    }
    dinv[g] = (deg > 0) ? (1.0f / sqrtf((float)deg)) : 0.0f;
    indeg[g] = ind;
  }
  s[threadIdx.x] = ind;
  __syncthreads();
  for (int off = 1; off < 1024; off <<= 1) {
    int tv = (threadIdx.x >= off) ? s[threadIdx.x - off] : 0;
    __syncthreads();
    s[threadIdx.x] += tv;
    __syncthreads();
  }
  if (g < N) ptr[g] = s[threadIdx.x] - ind;  // exclusive within block
  if (threadIdx.x == 1023) bsum[blockIdx.x] = s[1023];
}

// ---------- fused: scan bsum (per-block, in LDS) + finalize ptr + emit bases ----------
__global__ __launch_bounds__(256) void k_base(const int* __restrict__ partial,
                                              const int* __restrict__ bsum,
                                              int* __restrict__ ptr,
                                              int* __restrict__ base, int N, int nb) {
  __shared__ int pbs[64];
  if (threadIdx.x == 0) {
    int acc = 0;
    for (int i = 0; i < nb; ++i) { pbs[i] = acc; acc += bsum[i]; }
  }
  __syncthreads();
  int n = blockIdx.x * 256 + threadIdx.x;
  if (n >= N) return;
  int run = ptr[n] + pbs[n >> 10];
  ptr[n] = run;                      // final global exclusive scan
#pragma unroll
  for (int c = 0; c < NCHUNK; ++c) {
    base[(size_t)c * N + n] = run;
    run += partial[((size_t)NCHUNK + c) * N + n];
  }
}

// ---------- counting-sort binning (LDS atomics; base slice preloaded) ----------
__global__ __launch_bounds__(1024) void k_bin2(const int* __restrict__ ei,
                                               const int* __restrict__ base,
                                               int* __restrict__ csr_row,
                                               int N, int E, int range) {
  __shared__ int cnt[HIST_B];
  __shared__ int base_s[HIST_B];
  int c = blockIdx.x % NCHUNK;
  int r = blockIdx.x / NCHUNK;
  const int* row = ei;
  const int* col = ei + E;
  int lo = r * range;
  int hi = min(N, lo + range);
  int len = hi - lo;
  const int* bsrc = base + (size_t)c * N + lo;
  for (int i = threadIdx.x; i < len; i += 1024) {
    cnt[i] = 0;
    base_s[i] = bsrc[i];
  }
  __syncthreads();
  int e0 = (int)((long long)E * c / NCHUNK);
  int e1 = (int)((long long)E * (c + 1) / NCHUNK);
  for (int e = e0 + threadIdx.x; e < e1; e += 1024) {
    int cl = col[e];
    int rw = row[e];
    if (cl >= lo && cl < hi) {
      int off = atomicAdd(&cnt[cl - lo], 1);   // LDS atomic
      csr_row[base_s[cl - lo] + off] = rw;     // plain store (L2-absorbed)
    }
  }
}

// ---------- dual GEMM: t = h@Wn (bf16 out), agg = h@Wi + bias ----------
// h and agg may ALIAS (in-place layer 2): block owns rows [64b,64b+64),
// stages each 32-row group into LDS before overwriting it; groups disjoint.
template <bool RELU>
__global__ __launch_bounds__(256) void k_dual_gemm(
    const float* h,
    const float* __restrict__ Wn,
    const float* __restrict__ Wi,
    const float* __restrict__ bias,
    __hip_bfloat16* __restrict__ t, float* agg, int N) {
  __shared__ float Wn_s[64 * 64];
  __shared__ float Wi_s[64 * 64];
  __shared__ float b_s[64];
  __shared__ float h_s[32 * 68];   // 32 rows, stride 68 (pad kills store conflicts)

  const int tid = threadIdx.x;
  {
    const float4* Wn4 = (const float4*)Wn;
    const float4* Wi4 = (const float4*)Wi;
    for (int i = tid; i < 1024; i += 256) {
      ((float4*)Wn_s)[i] = Wn4[i];
      ((float4*)Wi_s)[i] = Wi4[i];
    }
  }
  if (tid < 64) b_s[tid] = bias[tid];

  const int j = tid & 63;      // output column
  const int rg = tid >> 6;     // row group 0..3 -> rows rg*8..rg*8+7
  const int r0 = blockIdx.x * 64;

  for (int g = 0; g < 2; ++g) {
    __syncthreads();  // protect h_s from prior readers; fences W staging (g=0)
    for (int v = tid; v < 512; v += 256) {
      int rr = v >> 4;
      int c4 = v & 15;
      int rload = r0 + g * 32 + rr;
      float4 val = make_float4(0.f, 0.f, 0.f, 0.f);
      if (rload < N) {
        val = *(const float4*)&h[(size_t)rload * 64 + c4 * 4];
        if (RELU) {
          val.x = fmaxf(val.x, 0.f); val.y = fmaxf(val.y, 0.f);
          val.z = fmaxf(val.z, 0.f); val.w = fmaxf(val.w, 0.f);
        }
      }
      *(float4*)&h_s[rr * 68 + c4 * 4] = val;
    }
    __syncthreads();

    float acc_t[8] = {0.f, 0.f, 0.f, 0.f, 0.f, 0.f, 0.f, 0.f};
    float acc_a[8] = {0.f, 0.f, 0.f, 0.f, 0.f, 0.f, 0.f, 0.f};
    for (int k4 = 0; k4 < 16; ++k4) {
      float4 hv[8];
#pragma unroll
      for (int r = 0; r < 8; ++r)
        hv[r] = *(const float4*)&h_s[(rg * 8 + r) * 68 + k4 * 4];
#pragma unroll
      for (int kk = 0; kk < 4; ++kk) {
        int k = k4 * 4 + kk;
        float wn = Wn_s[k * 64 + j];
        float wi = Wi_s[k * 64 + j];
#pragma unroll
        for (int r = 0; r < 8; ++r) {
          float hk = ((const float*)&hv[r])[kk];
          acc_t[r] = fmaf(hk, wn, acc_t[r]);
          acc_a[r] = fmaf(hk, wi, acc_a[r]);
        }
      }
    }
#pragma unroll
    for (int r = 0; r < 8; ++r) {
      int rr = r0 + g * 32 + rg * 8 + r;
      if (rr < N) {
        t[(size_t)rr * 64 + j] = __float2bfloat16(acc_t[r]);
        agg[(size_t)rr * 64 + j] = acc_a[r] + b_s[j];
      }
    }
  }
}

// ---------- CSR gather (layer 1): agg[n] += sum_e t[row_e]*norm ----------
// One wave per node; quarter-wave per edge (16 lanes x bf16x4 = full 128B row),
// unrolled 2 -> 8 edges in flight. Reduce across quarters with shfl_xor 16,32.
__global__ __launch_bounds__(256) void k_gather(
    const int* __restrict__ csr_row, const int* __restrict__ ptr,
    const int* __restrict__ indeg, const float* __restrict__ dinv,
    const __hip_bfloat16* __restrict__ t, float* __restrict__ agg, int N) {
  int n = blockIdx.x * 4 + (threadIdx.x >> 6);
  if (n >= N) return;
  int lane = threadIdx.x & 63;
  int q = lane >> 4;
  int fl = lane & 15;
  int i0 = ptr[n];
  int end = i0 + indeg[n];
  float dn = dinv[n];

  float4 acc = make_float4(0.f, 0.f, 0.f, 0.f);
  if (q == 0) acc = *(const float4*)&agg[(size_t)n * 64 + 4 * fl];

  int i = i0 + q;
  for (; i + 4 < end; i += 8) {
    int ra = csr_row[i];
    int rb = csr_row[i + 4];
    float na = dinv[ra] * dn;
    float nb = dinv[rb] * dn;
    ushort4 ua = *(const ushort4*)&t[(size_t)ra * 64 + 4 * fl];
    ushort4 ub = *(const ushort4*)&t[(size_t)rb * 64 + 4 * fl];
    float4 va, vb;
    ((unsigned*)&va)[0] = (unsigned)ua.x << 16; ((unsigned*)&va)[1] = (unsigned)ua.y << 16;
    ((unsigned*)&va)[2] = (unsigned)ua.z << 16; ((unsigned*)&va)[3] = (unsigned)ua.w << 16;
    ((unsigned*)&vb)[0] = (unsigned)ub.x << 16; ((unsigned*)&vb)[1] = (unsigned)ub.y << 16;
    ((unsigned*)&vb)[2] = (unsigned)ub.z << 16; ((unsigned*)&vb)[3] = (unsigned)ub.w << 16;
    acc.x = fmaf(va.x, na, acc.x); acc.y = fmaf(va.y, na, acc.y);
    acc.z = fmaf(va.z, na, acc.z); acc.w = fmaf(va.w, na, acc.w);
    acc.x = fmaf(vb.x, nb, acc.x); acc.y = fmaf(vb.y, nb, acc.y);
    acc.z = fmaf(vb.z, nb, acc.z); acc.w = fmaf(vb.w, nb, acc.w);
  }
  for (; i < end; i += 4) {
    int ra = csr_row[i];
    float na = dinv[ra] * dn;
    ushort4 ua = *(const ushort4*)&t[(size_t)ra * 64 + 4 * fl];
    float4 va;
    ((unsigned*)&va)[0] = (unsigned)ua.x << 16; ((unsigned*)&va)[1] = (unsigned)ua.y << 16;
    ((unsigned*)&va)[2] = (unsigned)ua.z << 16; ((unsigned*)&va)[3] = (unsigned)ua.w << 16;
    acc.x = fmaf(va.x, na, acc.x); acc.y = fmaf(va.y, na, acc.y);
    acc.z = fmaf(va.z, na, acc.z); acc.w = fmaf(va.w, na, acc.w);
  }
  acc.x += __shfl_xor(acc.x, 16); acc.y += __shfl_xor(acc.y, 16);
  acc.z += __shfl_xor(acc.z, 16); acc.w += __shfl_xor(acc.w, 16);
  acc.x += __shfl_xor(acc.x, 32); acc.y += __shfl_xor(acc.y, 32);
  acc.z += __shfl_xor(acc.z, 32); acc.w += __shfl_xor(acc.w, 32);
  if (q == 0) *(float4*)&agg[(size_t)n * 64 + 4 * fl] = acc;
}

// ---------- FUSED layer-2 gather + output GEMM ----------
// Same gather as above, but instead of writing agg, applies relu and computes
// out[n] = relu(row) @ Wo + bo in-wave (row staged in per-wave LDS buffer;
// half-wave k-split + shfl_xor(32) for the 64-deep dot products).
__global__ __launch_bounds__(256) void k_gather_out(
    const int* __restrict__ csr_row, const int* __restrict__ ptr,
    const int* __restrict__ indeg, const float* __restrict__ dinv,
    const __hip_bfloat16* __restrict__ t, const float* __restrict__ agg,
    const float* __restrict__ Wo,   // [64,32]
    const float* __restrict__ bo,   // [32]
    float* __restrict__ out, int N) {
  __shared__ float Wo_s[64 * 32];
  __shared__ float bo_s[32];
  __shared__ float rowbuf[4][64];

  const int tid = threadIdx.x;
  for (int i = tid; i < 2048; i += 256) Wo_s[i] = Wo[i];
  if (tid < 32) bo_s[tid] = bo[tid];
  __syncthreads();   // barrier BEFORE any divergent exit

  int w = tid >> 6;                 // wave id 0..3
  int n = blockIdx.x * 4 + w;
  if (n >= N) return;
  int lane = tid & 63;
  int q = lane >> 4;
  int fl = lane & 15;
  int i0 = ptr[n];
  int end = i0 + indeg[n];
  float dn = dinv[n];

  float4 acc = make_float4(0.f, 0.f, 0.f, 0.f);
  if (q == 0) acc = *(const float4*)&agg[(size_t)n * 64 + 4 * fl];

  int i = i0 + q;
  for (; i + 4 < end; i += 8) {
    int ra = csr_row[i];
    int rb = csr_row[i + 4];
    float na = dinv[ra] * dn;
    float nb = dinv[rb] * dn;
    ushort4 ua = *(const ushort4*)&t[(size_t)ra * 64 + 4 * fl];
    ushort4 ub = *(const ushort4*)&t[(size_t)rb * 64 + 4 * fl];
    float4 va, vb;
    ((unsigned*)&va)[0] = (unsigned)ua.x << 16; ((unsigned*)&va)[1] = (unsigned)ua.y << 16;
    ((unsigned*)&va)[2] = (unsigned)ua.z << 16; ((unsigned*)&va)[3] = (unsigned)ua.w << 16;
    ((unsigned*)&vb)[0] = (unsigned)ub.x << 16; ((unsigned*)&vb)[1] = (unsigned)ub.y << 16;
    ((unsigned*)&vb)[2] = (unsigned)ub.z << 16; ((unsigned*)&vb)[3] = (unsigned)ub.w << 16;
    acc.x = fmaf(va.x, na, acc.x); acc.y = fmaf(va.y, na, acc.y);
    acc.z = fmaf(va.z, na, acc.z); acc.w = fmaf(va.w, na, acc.w);
    acc.x = fmaf(vb.x, nb, acc.x); acc.y = fmaf(vb.y, nb, acc.y);
    acc.z = fmaf(vb.z, nb, acc.z); acc.w = fmaf(vb.w, nb, acc.w);
  }
  for (; i < end; i += 4) {
    int ra = csr_row[i];
    float na = dinv[ra] * dn;
    ushort4 ua = *(const ushort4*)&t[(size_t)ra * 64 + 4 * fl];
    float4 va;
    ((unsigned*)&va)[0] = (unsigned)ua.x << 16; ((unsigned*)&va)[1] = (unsigned)ua.y << 16;
    ((unsigned*)&va)[2] = (unsigned)ua.z << 16; ((unsigned*)&va)[3] = (unsigned)ua.w << 16;
    acc.x = fmaf(va.x, na, acc.x); acc.y = fmaf(va.y, na, acc.y);
    acc.z = fmaf(va.z, na, acc.z); acc.w = fmaf(va.w, na, acc.w);
  }
  acc.x += __shfl_xor(acc.x, 16); acc.y += __shfl_xor(acc.y, 16);
  acc.z += __shfl_xor(acc.z, 16); acc.w += __shfl_xor(acc.w, 16);
  acc.x += __shfl_xor(acc.x, 32); acc.y += __shfl_xor(acc.y, 32);
  acc.z += __shfl_xor(acc.z, 32); acc.w += __shfl_xor(acc.w, 32);
  // all quarters now hold the final row; q==0 stores relu(row) to rowbuf
  if (q == 0) {
    rowbuf[w][4 * fl + 0] = fmaxf(acc.x, 0.f);
    rowbuf[w][4 * fl + 1] = fmaxf(acc.y, 0.f);
    rowbuf[w][4 * fl + 2] = fmaxf(acc.z, 0.f);
    rowbuf[w][4 * fl + 3] = fmaxf(acc.w, 0.f);
  }
  // same-wave LDS RAW: compiler inserts lgkmcnt wait; no barrier needed.
  int half = lane >> 5;      // k-range half
  int j = lane & 31;         // output column
  float o = 0.f;
#pragma unroll 8
  for (int k = 32 * half; k < 32 * half + 32; ++k)
    o = fmaf(rowbuf[w][k], Wo_s[k * 32 + j], o);
  o += __shfl_xor(o, 32);
  if (half == 0) out[(size_t)n * 32 + j] = o + bo_s[j];
}

extern "C" void kernel_launch(void* const* d_in, const int* in_sizes, int n_in,
                              void* d_out, int out_size, void* d_ws, size_t ws_size,
                              hipStream_t stream) {
  const float* x = (const float*)d_in[0];
  const int* ei = (const int*)d_in[1];
  const float* W_in1 = (const float*)d_in[2];
  const float* W_neigh1 = (const float*)d_in[3];
  const float* bias1 = (const float*)d_in[4];
  const float* W_in2 = (const float*)d_in[5];
  const float* W_neigh2 = (const float*)d_in[6];
  const float* bias2 = (const float*)d_in[7];
  const float* W_out = (const float*)d_in[8];
  const float* b_out = (const float*)d_in[9];
  float* out = (float*)d_out;

  const int N = in_sizes[0] / 64;
  const int E = in_sizes[1] / 2;

  char* ws = (char*)d_ws;
  size_t off = 0;
  auto alloc = [&](size_t bytes) -> void* {
    void* p = ws + off;
    off += (bytes + 255) & ~(size_t)255;
    return p;
  };
  float* dinv = (float*)alloc((size_t)N * 4);
  int* indeg = (int*)alloc((size_t)N * 4);
  int* ptr = (int*)alloc((size_t)N * 4);
  int* bsum = (int*)alloc(256);
  int* csr_row = (int*)alloc((size_t)E * 4);
  int* partial = (int*)alloc((size_t)2 * NCHUNK * N * 4);
  int* base = (int*)alloc((size_t)NCHUNK * N * 4);
  __hip_bfloat16* t = (__hip_bfloat16*)alloc((size_t)N * 64 * 2);
  float* agg = (float*)alloc((size_t)N * 64 * 4);
  (void)ws_size;

  int range_h = (N + NRANGE_H - 1) / NRANGE_H;  // 12500 <= HIST_H
  int range_b = (N + NRANGE_B - 1) / NRANGE_B;  // 6250  <= HIST_B
  int gN = (N + 255) / 256;
  int gRows = (N + 63) / 64;
  int gNode = (N + 3) / 4;
  int nb = (N + 1023) / 1024;

  k_hist<<<2 * NRANGE_H * NCHUNK, 1024, 0, stream>>>(ei, partial, N, E, range_h);
  k_dinv_scan<<<nb, 1024, 0, stream>>>(partial, dinv, indeg, ptr, bsum, N);
  k_base<<<gN, 256, 0, stream>>>(partial, bsum, ptr, base, N, nb);
  k_bin2<<<NRANGE_B * NCHUNK, 1024, 0, stream>>>(ei, base, csr_row, N, E, range_b);

  // layer 1
  k_dual_gemm<false><<<gRows, 256, 0, stream>>>(x, W_neigh1, W_in1, bias1, t, agg, N);
  k_gather<<<gNode, 256, 0, stream>>>(csr_row, ptr, indeg, dinv, t, agg, N);

  // layer 2 (in-place on agg), then fused gather+output
  k_dual_gemm<true><<<gRows, 256, 0, stream>>>(agg, W_neigh2, W_in2, bias2, t, agg, N);
  k_gather_out<<<gNode, 256, 0, stream>>>(csr_row, ptr, indeg, dinv, t, agg,
                                          W_out, b_out, out, N);
}